// Round 3
// baseline (1491.870 us; speedup 1.0000x reference)
//
#include <hip/hip_runtime.h>
#include <hip/hip_bf16.h>

#define NN   50000
#define NE   1600000
#define D    128
#define NBUK 196      // ceil(NN/256) buckets of 256 nodes
#define EPB  2048     // edges per block in hist/fill

typedef __attribute__((ext_vector_type(8))) short short8;
typedef __attribute__((ext_vector_type(4))) float f32x4;

__device__ __forceinline__ unsigned short f2b(float x) {
  unsigned u = __float_as_uint(x);
  u += 0x7fffu + ((u >> 16) & 1u);
  return (unsigned short)(u >> 16);
}
__device__ __forceinline__ float b2f(unsigned short v) {
  return __uint_as_float(((unsigned)v) << 16);
}

// int64 vs int32 edge_index detection (odd int32 words all-zero => int64).
__global__ void detect_k(const int* __restrict__ ei, int* __restrict__ flag) {
  __shared__ int nz;
  if (threadIdx.x == 0) nz = 0;
  __syncthreads();
  int idx = 1 + 2 * ((int)threadIdx.x * (NE / 256));
  if (ei[idx] != 0) atomicOr(&nz, 1);
  __syncthreads();
  if (threadIdx.x == 0) *flag = (nz == 0) ? 1 : 0;  // 1 => int64
}

// hb = bf16(h); zero the bucket histogram.
__global__ __launch_bounds__(256) void prep_k(const float* __restrict__ h,
                                              unsigned short* __restrict__ hb,
                                              int* __restrict__ gcnt) {
  int i = blockIdx.x * 256 + threadIdx.x;  // one float4-group, 1.6M threads
  float4 x = ((const float4*)h)[i];
  ushort4 o;
  o.x = f2b(x.x); o.y = f2b(x.y); o.z = f2b(x.z); o.w = f2b(x.w);
  ((ushort4*)hb)[i] = o;
  if (i < NBUK) gcnt[i] = 0;
}

// W1 = W_upd[:, :128] -> bf16 ; Wc = W_upd[:, 128:] @ W_msg -> bf16
__global__ __launch_bounds__(256) void wprep_k(const float* __restrict__ Wm,
                                               const float* __restrict__ Wu,
                                               unsigned short* __restrict__ W1b,
                                               unsigned short* __restrict__ Wcb) {
  int tid = blockIdx.x * 256 + threadIdx.x;  // 0..16383
  int o = tid >> 7, j = tid & 127;
  W1b[tid] = f2b(Wu[o * 256 + j]);
  float acc = 0.f;
#pragma unroll 4
  for (int k = 0; k < 128; ++k)
    acc += Wu[o * 256 + 128 + k] * Wm[k * 128 + j];
  Wcb[tid] = f2b(acc);
}

// Bucket histogram: LDS-privatized, one global atomic per (block,bucket).
__global__ __launch_bounds__(256) void bhist_k(const int* __restrict__ ei,
                                               const int* __restrict__ flag,
                                               int* __restrict__ gcnt) {
  __shared__ int cnt[NBUK];
  for (int t = threadIdx.x; t < NBUK; t += 256) cnt[t] = 0;
  __syncthreads();
  const int f = *flag;
  const int e0 = blockIdx.x * EPB + threadIdx.x * 8;
#pragma unroll
  for (int j = 0; j < 8; ++j) {
    int e = e0 + j;
    if (e < NE) {
      int dst = f ? ei[2 * ((size_t)NE + e)] : ei[NE + e];
      atomicAdd(&cnt[dst >> 8], 1);
    }
  }
  __syncthreads();
  for (int t = threadIdx.x; t < NBUK; t += 256)
    if (cnt[t]) atomicAdd(&gcnt[t], cnt[t]);
}

// Exclusive scan of the 196 bucket counts; init cursor. One block.
__global__ __launch_bounds__(256) void bscan_k(const int* __restrict__ gcnt,
                                               int* __restrict__ bases,
                                               int* __restrict__ gcursor) {
  __shared__ int wsum[4];
  const int tid = threadIdx.x, lane = tid & 63, wv = tid >> 6;
  int v = (tid < NBUK) ? gcnt[tid] : 0;
  int s = v;
#pragma unroll
  for (int d = 1; d < 64; d <<= 1) {
    int t = __shfl_up(s, d, 64);
    if (lane >= d) s += t;
  }
  if (lane == 63) wsum[wv] = s;
  __syncthreads();
  int woff = 0;
  for (int k = 0; k < wv; ++k) woff += wsum[k];
  int excl = woff + s - v;
  if (tid < NBUK) { bases[tid] = excl; gcursor[tid] = excl; }
  if (tid == 0) bases[NBUK] = NE;
}

// Bucket the edges: LDS local ranks + one bulk reservation per (block,bucket),
// then write packed (dstLocal<<16 | src) into the bucket's contiguous chunk.
__global__ __launch_bounds__(256) void bfill_k(const int* __restrict__ ei,
                                               const int* __restrict__ flag,
                                               int* __restrict__ gcursor,
                                               unsigned* __restrict__ ebuf) {
  __shared__ int cnt[NBUK];
  __shared__ int off[NBUK];
  for (int t = threadIdx.x; t < NBUK; t += 256) cnt[t] = 0;
  __syncthreads();
  const int f = *flag;
  const int e0 = blockIdx.x * EPB + threadIdx.x * 8;
  unsigned pk[8]; int bk[8]; int lr[8];
#pragma unroll
  for (int j = 0; j < 8; ++j) {
    int e = e0 + j;
    bk[j] = -1;
    if (e < NE) {
      int src = f ? ei[2 * (size_t)e] : ei[e];
      int dst = f ? ei[2 * ((size_t)NE + e)] : ei[NE + e];
      bk[j] = dst >> 8;
      pk[j] = (unsigned)src | ((unsigned)(dst & 255) << 16);
      lr[j] = atomicAdd(&cnt[bk[j]], 1);
    }
  }
  __syncthreads();
  for (int t = threadIdx.x; t < NBUK; t += 256)
    off[t] = cnt[t] ? atomicAdd(&gcursor[t], cnt[t]) : 0;
  __syncthreads();
#pragma unroll
  for (int j = 0; j < 8; ++j)
    if (bk[j] >= 0) ebuf[off[bk[j]] + lr[j]] = pk[j];
}

// One block per bucket: accumulate 256 node rows in LDS fp32 via ds-atomics.
// accLo holds even channels (2*lane), accHi odd -> bank = lane%32, conflict-free.
__global__ __launch_bounds__(512) void bagg_k(const unsigned* __restrict__ ebuf,
                                              const int* __restrict__ bases,
                                              const unsigned short* __restrict__ hb,
                                              unsigned short* __restrict__ Sb) {
  __shared__ float accLo[256 * 64];
  __shared__ float accHi[256 * 64];
  const int b = blockIdx.x;
  const int tid = threadIdx.x, l = tid & 63, wv = tid >> 6;  // 8 waves
  for (int i = tid; i < 256 * 64; i += 512) { accLo[i] = 0.f; accHi[i] = 0.f; }
  __syncthreads();
  const int beg = bases[b], end = bases[b + 1];
  for (int e0 = beg + wv * 16; e0 < end; e0 += 128) {
    const int m = min(16, end - e0);
    unsigned p[16]; unsigned v[16];
#pragma unroll
    for (int j = 0; j < 16; ++j) {
      if (j < m) {
        p[j] = ebuf[e0 + j];
        v[j] = *(const unsigned*)(hb + (size_t)(p[j] & 0xffffu) * D + 2 * l);
      }
    }
#pragma unroll
    for (int j = 0; j < 16; ++j) {
      if (j < m) {
        const int dl = (int)(p[j] >> 16);
        atomicAdd(&accLo[dl * 64 + l], b2f((unsigned short)(v[j] & 0xffffu)));
        atomicAdd(&accHi[dl * 64 + l], b2f((unsigned short)(v[j] >> 16)));
      }
    }
  }
  __syncthreads();
  const int node0 = b << 8;
  for (int i = tid; i < 256 * 64; i += 512) {
    const int row = i >> 6, pr = i & 63;
    const int node = node0 + row;
    if (node < NN) {
      unsigned o = (unsigned)f2b(accLo[i]) | ((unsigned)f2b(accHi[i]) << 16);
      *(unsigned*)(Sb + (size_t)node * D + 2 * pr) = o;
    }
  }
}

// out = relu([h | agg] @ [W1 | Wc]^T + b), bf16 MFMA 16x16x32, K=256, N=128.
__global__ __launch_bounds__(256) void gemm_k(const unsigned short* __restrict__ hb,
                                              const unsigned short* __restrict__ Sb,
                                              const unsigned short* __restrict__ W1b,
                                              const unsigned short* __restrict__ Wcb,
                                              const float* __restrict__ bias,
                                              float* __restrict__ out) {
  const int wave = threadIdx.x >> 6;
  const int lane = threadIdx.x & 63;
  const int r = lane & 15;
  const int g = lane >> 4;
  const int row0 = blockIdx.x * 64 + wave * 16;
  const int row = min(row0 + r, NN - 1);

  f32x4 acc[8];
#pragma unroll
  for (int t = 0; t < 8; ++t) acc[t] = (f32x4){0.f, 0.f, 0.f, 0.f};

#pragma unroll
  for (int c = 0; c < 8; ++c) {
    const int k0 = (c & 3) * 32 + g * 8;
    const unsigned short* A = (c < 4) ? hb : Sb;
    short8 a = *(const short8*)(A + (size_t)row * D + k0);
    const unsigned short* W = (c < 4) ? W1b : Wcb;
#pragma unroll
    for (int t = 0; t < 8; ++t) {
      short8 bfr = *(const short8*)(W + (size_t)(t * 16 + r) * D + k0);
      acc[t] = __builtin_amdgcn_mfma_f32_16x16x32_bf16(a, bfr, acc[t], 0, 0, 0);
    }
  }

#pragma unroll
  for (int t = 0; t < 8; ++t) {
    const int col = t * 16 + r;
    const float bv = bias[col];
#pragma unroll
    for (int j = 0; j < 4; ++j) {
      const int orow = row0 + g * 4 + j;
      if (orow < NN) {
        float v = acc[t][j] + bv;
        out[(size_t)orow * D + col] = v > 0.f ? v : 0.f;
      }
    }
  }
}

extern "C" void kernel_launch(void* const* d_in, const int* in_sizes, int n_in,
                              void* d_out, int out_size, void* d_ws, size_t ws_size,
                              hipStream_t stream) {
  const float* h  = (const float*)d_in[0];
  const int*   ei = (const int*)d_in[1];
  const float* Wm = (const float*)d_in[2];
  const float* Wu = (const float*)d_in[3];
  const float* bu = (const float*)d_in[4];
  float* out = (float*)d_out;

  char* ws = (char*)d_ws;
  unsigned short* Sb   = (unsigned short*)(ws);              // 12,800,000 B
  unsigned short* hb   = (unsigned short*)(ws + 12800000);   // 12,800,000 B
  unsigned*       ebuf = (unsigned*)(ws + 25600000);         //  6,400,000 B
  int*            gcnt = (int*)(ws + 32000000);              //      1,024 B
  int*            bas  = (int*)(ws + 32001024);              //      1,024 B
  int*            gcur = (int*)(ws + 32002048);              //      1,024 B
  unsigned short* W1b  = (unsigned short*)(ws + 32003072);   //     32,768 B
  unsigned short* Wcb  = (unsigned short*)(ws + 32035840);   //     32,768 B
  int*            flg  = (int*)(ws + 32068608);              //          4 B

  detect_k<<<1, 256, 0, stream>>>(ei, flg);
  prep_k<<<(NN * D / 4) / 256, 256, 0, stream>>>(h, hb, gcnt);       // 6250 blocks
  wprep_k<<<64, 256, 0, stream>>>(Wm, Wu, W1b, Wcb);
  bhist_k<<<(NE + EPB - 1) / EPB, 256, 0, stream>>>(ei, flg, gcnt);  // 782 blocks
  bscan_k<<<1, 256, 0, stream>>>(gcnt, bas, gcur);
  bfill_k<<<(NE + EPB - 1) / EPB, 256, 0, stream>>>(ei, flg, gcur, ebuf);
  bagg_k<<<NBUK, 512, 0, stream>>>(ebuf, bas, hb, Sb);               // 196 blocks
  gemm_k<<<(NN + 63) / 64, 256, 0, stream>>>(hb, Sb, W1b, Wcb, bu, out);
}

// Round 4
// 194.135 us; speedup vs baseline: 7.6847x; 7.6847x over previous
//
#include <hip/hip_runtime.h>
#include <hip/hip_bf16.h>

#define NN   50000
#define NE   1600000
#define D    128
#define NBUK 196      // ceil(NN/256) buckets of 256 nodes
#define EPB  2048     // edges per block in hist/fill

typedef __attribute__((ext_vector_type(8))) short short8;
typedef __attribute__((ext_vector_type(4))) float f32x4;

__device__ __forceinline__ unsigned short f2b(float x) {
  unsigned u = __float_as_uint(x);
  u += 0x7fffu + ((u >> 16) & 1u);
  return (unsigned short)(u >> 16);
}
__device__ __forceinline__ float b2f(unsigned short v) {
  return __uint_as_float(((unsigned)v) << 16);
}

// int64 vs int32 edge_index detection (odd int32 words all-zero => int64).
__global__ void detect_k(const int* __restrict__ ei, int* __restrict__ flag) {
  __shared__ int nz;
  if (threadIdx.x == 0) nz = 0;
  __syncthreads();
  int idx = 1 + 2 * ((int)threadIdx.x * (NE / 256));
  if (ei[idx] != 0) atomicOr(&nz, 1);
  __syncthreads();
  if (threadIdx.x == 0) *flag = (nz == 0) ? 1 : 0;  // 1 => int64
}

// hb = bf16(h); zero the bucket histogram.
__global__ __launch_bounds__(256) void prep_k(const float* __restrict__ h,
                                              unsigned short* __restrict__ hb,
                                              int* __restrict__ gcnt) {
  int i = blockIdx.x * 256 + threadIdx.x;  // one float4-group, 1.6M threads
  float4 x = ((const float4*)h)[i];
  ushort4 o;
  o.x = f2b(x.x); o.y = f2b(x.y); o.z = f2b(x.z); o.w = f2b(x.w);
  ((ushort4*)hb)[i] = o;
  if (i < NBUK) gcnt[i] = 0;
}

// W1 = W_upd[:, :128] -> bf16 ; Wc = W_upd[:, 128:] @ W_msg -> bf16
__global__ __launch_bounds__(256) void wprep_k(const float* __restrict__ Wm,
                                               const float* __restrict__ Wu,
                                               unsigned short* __restrict__ W1b,
                                               unsigned short* __restrict__ Wcb) {
  int tid = blockIdx.x * 256 + threadIdx.x;  // 0..16383
  int o = tid >> 7, j = tid & 127;
  W1b[tid] = f2b(Wu[o * 256 + j]);
  float acc = 0.f;
#pragma unroll 4
  for (int k = 0; k < 128; ++k)
    acc += Wu[o * 256 + 128 + k] * Wm[k * 128 + j];
  Wcb[tid] = f2b(acc);
}

// Bucket histogram: LDS-privatized, one global atomic per (block,bucket).
__global__ __launch_bounds__(256) void bhist_k(const int* __restrict__ ei,
                                               const int* __restrict__ flag,
                                               int* __restrict__ gcnt) {
  __shared__ int cnt[NBUK];
  for (int t = threadIdx.x; t < NBUK; t += 256) cnt[t] = 0;
  __syncthreads();
  const int f = *flag;
  const int e0 = blockIdx.x * EPB + threadIdx.x * 8;
#pragma unroll
  for (int j = 0; j < 8; ++j) {
    int e = e0 + j;
    if (e < NE) {
      int dst = f ? ei[2 * ((size_t)NE + e)] : ei[NE + e];
      atomicAdd(&cnt[dst >> 8], 1);
    }
  }
  __syncthreads();
  for (int t = threadIdx.x; t < NBUK; t += 256)
    if (cnt[t]) atomicAdd(&gcnt[t], cnt[t]);
}

// Exclusive scan of the 196 bucket counts; init cursor. One block.
__global__ __launch_bounds__(256) void bscan_k(const int* __restrict__ gcnt,
                                               int* __restrict__ bases,
                                               int* __restrict__ gcursor) {
  __shared__ int wsum[4];
  const int tid = threadIdx.x, lane = tid & 63, wv = tid >> 6;
  int v = (tid < NBUK) ? gcnt[tid] : 0;
  int s = v;
#pragma unroll
  for (int d = 1; d < 64; d <<= 1) {
    int t = __shfl_up(s, d, 64);
    if (lane >= d) s += t;
  }
  if (lane == 63) wsum[wv] = s;
  __syncthreads();
  int woff = 0;
  for (int k = 0; k < wv; ++k) woff += wsum[k];
  int excl = woff + s - v;
  if (tid < NBUK) { bases[tid] = excl; gcursor[tid] = excl; }
  if (tid == 0) bases[NBUK] = NE;
}

// Bucket the edges: LDS local ranks + one bulk reservation per (block,bucket),
// then write packed (dstLocal<<16 | src) into the bucket's contiguous chunk.
__global__ __launch_bounds__(256) void bfill_k(const int* __restrict__ ei,
                                               const int* __restrict__ flag,
                                               int* __restrict__ gcursor,
                                               unsigned* __restrict__ ebuf) {
  __shared__ int cnt[NBUK];
  __shared__ int off[NBUK];
  for (int t = threadIdx.x; t < NBUK; t += 256) cnt[t] = 0;
  __syncthreads();
  const int f = *flag;
  const int e0 = blockIdx.x * EPB + threadIdx.x * 8;
  unsigned pk[8]; int bk[8]; int lr[8];
#pragma unroll
  for (int j = 0; j < 8; ++j) {
    int e = e0 + j;
    bk[j] = -1;
    if (e < NE) {
      int src = f ? ei[2 * (size_t)e] : ei[e];
      int dst = f ? ei[2 * ((size_t)NE + e)] : ei[NE + e];
      bk[j] = dst >> 8;
      pk[j] = (unsigned)src | ((unsigned)(dst & 255) << 16);
      lr[j] = atomicAdd(&cnt[bk[j]], 1);
    }
  }
  __syncthreads();
  for (int t = threadIdx.x; t < NBUK; t += 256)
    off[t] = cnt[t] ? atomicAdd(&gcursor[t], cnt[t]) : 0;
  __syncthreads();
#pragma unroll
  for (int j = 0; j < 8; ++j)
    if (bk[j] >= 0) ebuf[off[bk[j]] + lr[j]] = pk[j];
}

// Block-local counting sort per bucket: 256-counter LDS histogram + scan,
// then write src (ushort) into node-sorted order; emit per-node offs.
__global__ __launch_bounds__(512) void nsort_k(const unsigned* __restrict__ ebuf,
                                               const int* __restrict__ bases,
                                               int* __restrict__ offs,
                                               unsigned short* __restrict__ srt) {
  __shared__ int cnt[256];
  __shared__ int cur[256];
  __shared__ int wsum[4];
  const int b = blockIdx.x, tid = threadIdx.x;
  const int lane = tid & 63, wv = tid >> 6;
  if (tid < 256) cnt[tid] = 0;
  __syncthreads();
  const int beg = bases[b], end = bases[b + 1];
  for (int e = beg + tid; e < end; e += 512)
    atomicAdd(&cnt[ebuf[e] >> 16], 1);
  __syncthreads();
  int v = 0, s = 0;
  if (tid < 256) {  // waves 0..3, wave-uniform branch
    v = cnt[tid]; s = v;
#pragma unroll
    for (int d = 1; d < 64; d <<= 1) {
      int t = __shfl_up(s, d, 64);
      if (lane >= d) s += t;
    }
    if (lane == 63) wsum[wv] = s;
  }
  __syncthreads();
  if (tid < 256) {
    int woff = 0;
    for (int k = 0; k < wv; ++k) woff += wsum[k];
    int excl = woff + s - v;
    cur[tid] = beg + excl;
    int node = (b << 8) + tid;
    if (node < NN) offs[node] = beg + excl;
  }
  if (b == NBUK - 1 && tid == 0) offs[NN] = NE;
  __syncthreads();
  for (int e = beg + tid; e < end; e += 512) {
    unsigned p = ebuf[e];
    int slot = atomicAdd(&cur[p >> 16], 1);
    srt[slot] = (unsigned short)(p & 0xffffu);
  }
}

// One wave per node: sum bf16 rows of its in-edges in fp32 regs (2 ch/lane),
// write the aggregated row once as bf16.
__global__ __launch_bounds__(256) void agg_k(const unsigned short* __restrict__ srt,
                                             const int* __restrict__ offs,
                                             const unsigned short* __restrict__ hb,
                                             unsigned short* __restrict__ Sb) {
  const int w = (int)((blockIdx.x * 256u + threadIdx.x) >> 6);  // node id
  const int l = threadIdx.x & 63;
  const int beg = offs[w], end = offs[w + 1];
  float ax = 0.f, ay = 0.f;
  int e = beg;
  for (; e + 8 <= end; e += 8) {
    unsigned v[8];
#pragma unroll
    for (int j = 0; j < 8; ++j) {
      int s = srt[e + j];
      v[j] = *(const unsigned*)(hb + (size_t)s * D + 2 * l);
    }
#pragma unroll
    for (int j = 0; j < 8; ++j) {
      ax += b2f((unsigned short)(v[j] & 0xffffu));
      ay += b2f((unsigned short)(v[j] >> 16));
    }
  }
  for (; e < end; ++e) {
    unsigned v = *(const unsigned*)(hb + (size_t)srt[e] * D + 2 * l);
    ax += b2f((unsigned short)(v & 0xffffu));
    ay += b2f((unsigned short)(v >> 16));
  }
  unsigned o = (unsigned)f2b(ax) | ((unsigned)f2b(ay) << 16);
  *(unsigned*)(Sb + (size_t)w * D + 2 * l) = o;
}

// out = relu([h | agg] @ [W1 | Wc]^T + b), bf16 MFMA 16x16x32, K=256, N=128.
__global__ __launch_bounds__(256) void gemm_k(const unsigned short* __restrict__ hb,
                                              const unsigned short* __restrict__ Sb,
                                              const unsigned short* __restrict__ W1b,
                                              const unsigned short* __restrict__ Wcb,
                                              const float* __restrict__ bias,
                                              float* __restrict__ out) {
  const int wave = threadIdx.x >> 6;
  const int lane = threadIdx.x & 63;
  const int r = lane & 15;
  const int g = lane >> 4;
  const int row0 = blockIdx.x * 64 + wave * 16;
  const int row = min(row0 + r, NN - 1);

  f32x4 acc[8];
#pragma unroll
  for (int t = 0; t < 8; ++t) acc[t] = (f32x4){0.f, 0.f, 0.f, 0.f};

#pragma unroll
  for (int c = 0; c < 8; ++c) {
    const int k0 = (c & 3) * 32 + g * 8;
    const unsigned short* A = (c < 4) ? hb : Sb;
    short8 a = *(const short8*)(A + (size_t)row * D + k0);
    const unsigned short* W = (c < 4) ? W1b : Wcb;
#pragma unroll
    for (int t = 0; t < 8; ++t) {
      short8 bfr = *(const short8*)(W + (size_t)(t * 16 + r) * D + k0);
      acc[t] = __builtin_amdgcn_mfma_f32_16x16x32_bf16(a, bfr, acc[t], 0, 0, 0);
    }
  }

#pragma unroll
  for (int t = 0; t < 8; ++t) {
    const int col = t * 16 + r;
    const float bv = bias[col];
#pragma unroll
    for (int j = 0; j < 4; ++j) {
      const int orow = row0 + g * 4 + j;
      if (orow < NN) {
        float v = acc[t][j] + bv;
        out[(size_t)orow * D + col] = v > 0.f ? v : 0.f;
      }
    }
  }
}

extern "C" void kernel_launch(void* const* d_in, const int* in_sizes, int n_in,
                              void* d_out, int out_size, void* d_ws, size_t ws_size,
                              hipStream_t stream) {
  const float* h  = (const float*)d_in[0];
  const int*   ei = (const int*)d_in[1];
  const float* Wm = (const float*)d_in[2];
  const float* Wu = (const float*)d_in[3];
  const float* bu = (const float*)d_in[4];
  float* out = (float*)d_out;

  char* ws = (char*)d_ws;
  unsigned short* Sb   = (unsigned short*)(ws);              // 12,800,000 B
  unsigned short* hb   = (unsigned short*)(ws + 12800000);   // 12,800,000 B
  unsigned*       ebuf = (unsigned*)(ws + 25600000);         //  6,400,000 B
  unsigned short* srt  = (unsigned short*)(ws + 32000000);   //  3,200,000 B
  int*            offs = (int*)(ws + 35200000);              //    200,016 B (NN+1)
  int*            gcnt = (int*)(ws + 35400016);              //      1,024 B
  int*            bas  = (int*)(ws + 35401040);              //      1,024 B
  int*            gcur = (int*)(ws + 35402064);              //      1,024 B
  unsigned short* W1b  = (unsigned short*)(ws + 35403088);   //     32,768 B
  unsigned short* Wcb  = (unsigned short*)(ws + 35435856);   //     32,768 B
  int*            flg  = (int*)(ws + 35468624);              //          4 B

  detect_k<<<1, 256, 0, stream>>>(ei, flg);
  prep_k<<<(NN * D / 4) / 256, 256, 0, stream>>>(h, hb, gcnt);       // 6250 blocks
  wprep_k<<<64, 256, 0, stream>>>(Wm, Wu, W1b, Wcb);
  bhist_k<<<(NE + EPB - 1) / EPB, 256, 0, stream>>>(ei, flg, gcnt);  // 782 blocks
  bscan_k<<<1, 256, 0, stream>>>(gcnt, bas, gcur);
  bfill_k<<<(NE + EPB - 1) / EPB, 256, 0, stream>>>(ei, flg, gcur, ebuf);
  nsort_k<<<NBUK, 512, 0, stream>>>(ebuf, bas, offs, srt);           // 196 blocks
  agg_k<<<(NN * 64) / 256, 256, 0, stream>>>(srt, offs, hb, Sb);     // 12500 blocks
  gemm_k<<<(NN + 63) / 64, 256, 0, stream>>>(hb, Sb, W1b, Wcb, bu, out);
}

// Round 5
// 174.754 us; speedup vs baseline: 8.5370x; 1.1109x over previous
//
#include <hip/hip_runtime.h>
#include <hip/hip_bf16.h>

#define NN   50000
#define NE   1600000
#define D    128
#define NBUK 196      // ceil(NN/256) buckets of 256 nodes
#define EPB  2048     // edges per block in hist/fill

typedef __attribute__((ext_vector_type(8))) short short8;
typedef __attribute__((ext_vector_type(4))) float f32x4;

__device__ __forceinline__ unsigned short f2b(float x) {
  unsigned u = __float_as_uint(x);
  u += 0x7fffu + ((u >> 16) & 1u);
  return (unsigned short)(u >> 16);
}
__device__ __forceinline__ float b2f(unsigned short v) {
  return __uint_as_float(((unsigned)v) << 16);
}

// Fused: prep (h->bf16, zero cnt/cur) | wprep (fold W2@Wmsg) | int64-detect.
__global__ __launch_bounds__(256) void init_k(const float* __restrict__ h,
                                              unsigned short* __restrict__ hb,
                                              int* __restrict__ gcnt,
                                              int* __restrict__ gcur,
                                              const float* __restrict__ Wm,
                                              const float* __restrict__ Wu,
                                              unsigned short* __restrict__ W1b,
                                              unsigned short* __restrict__ Wcb,
                                              const int* __restrict__ ei,
                                              int* __restrict__ flg) {
  __shared__ int nz;
  const int blk = blockIdx.x;
  if (blk < 6250) {                     // prep: 6250*256 float4 groups
    int i = blk * 256 + threadIdx.x;
    float4 x = ((const float4*)h)[i];
    ushort4 o;
    o.x = f2b(x.x); o.y = f2b(x.y); o.z = f2b(x.z); o.w = f2b(x.w);
    ((ushort4*)hb)[i] = o;
    if (i < NBUK) { gcnt[i] = 0; gcur[i] = 0; }
  } else if (blk < 6314) {              // wprep: 64 blocks -> 16384 threads
    int tid = (blk - 6250) * 256 + threadIdx.x;
    int o = tid >> 7, j = tid & 127;
    W1b[tid] = f2b(Wu[o * 256 + j]);
    float acc = 0.f;
#pragma unroll 4
    for (int k = 0; k < 128; ++k)
      acc += Wu[o * 256 + 128 + k] * Wm[k * 128 + j];
    Wcb[tid] = f2b(acc);
  } else {                              // detect: odd int32 words all-zero => int64
    if (threadIdx.x == 0) nz = 0;
    __syncthreads();
    int idx = 1 + 2 * ((int)threadIdx.x * (NE / 256));
    if (ei[idx] != 0) atomicOr(&nz, 1);
    __syncthreads();
    if (threadIdx.x == 0) *flg = (nz == 0) ? 1 : 0;
  }
}

// Bucket histogram: vectorized edge loads, LDS-privatized counters,
// one global atomic per (block,bucket).
__global__ __launch_bounds__(256) void bhist_k(const int* __restrict__ ei,
                                               const int* __restrict__ flag,
                                               int* __restrict__ gcnt) {
  __shared__ int cnt[NBUK];
  if (threadIdx.x < NBUK) cnt[threadIdx.x] = 0;
  __syncthreads();
  const int f = *flag;
  const int e0 = blockIdx.x * EPB + threadIdx.x * 8;
  if (e0 + 8 <= NE) {
    int dv[8];
    if (f) {
      const int4* p = (const int4*)(ei + 2 * (size_t)NE + 2 * (size_t)e0);
      int4 a = p[0], b = p[1], c = p[2], d = p[3];
      dv[0]=a.x; dv[1]=a.z; dv[2]=b.x; dv[3]=b.z; dv[4]=c.x; dv[5]=c.z; dv[6]=d.x; dv[7]=d.z;
    } else {
      const int4* p = (const int4*)(ei + (size_t)NE + e0);
      int4 a = p[0], b = p[1];
      dv[0]=a.x; dv[1]=a.y; dv[2]=a.z; dv[3]=a.w; dv[4]=b.x; dv[5]=b.y; dv[6]=b.z; dv[7]=b.w;
    }
#pragma unroll
    for (int j = 0; j < 8; ++j) atomicAdd(&cnt[dv[j] >> 8], 1);
  } else {
    for (int j = 0; j < 8; ++j) {
      int e = e0 + j;
      if (e < NE) {
        int dst = f ? ei[2 * ((size_t)NE + e)] : ei[NE + e];
        atomicAdd(&cnt[dst >> 8], 1);
      }
    }
  }
  __syncthreads();
  if (threadIdx.x < NBUK && cnt[threadIdx.x])
    atomicAdd(&gcnt[threadIdx.x], cnt[threadIdx.x]);
}

// Bucket the edges. Local scan of gcnt -> bases (no separate scan kernel);
// LDS local ranks + one bulk reservation per (block,bucket); packed
// (dstLocal<<16 | src) written into the bucket's contiguous chunk.
__global__ __launch_bounds__(256) void bfill_k(const int* __restrict__ ei,
                                               const int* __restrict__ flag,
                                               const int* __restrict__ gcnt,
                                               int* __restrict__ gcur,
                                               unsigned* __restrict__ ebuf) {
  __shared__ int lbase[NBUK];
  __shared__ int cnt[NBUK];
  __shared__ int off[NBUK];
  __shared__ int wsum[4];
  const int tid = threadIdx.x, lane = tid & 63, wv = tid >> 6;
  if (tid < NBUK) cnt[tid] = 0;
  int v = (tid < NBUK) ? gcnt[tid] : 0;
  int s = v;
#pragma unroll
  for (int d = 1; d < 64; d <<= 1) {
    int t = __shfl_up(s, d, 64);
    if (lane >= d) s += t;
  }
  if (lane == 63) wsum[wv] = s;
  __syncthreads();
  {
    int woff = 0;
    for (int k = 0; k < wv; ++k) woff += wsum[k];
    if (tid < NBUK) lbase[tid] = woff + s - v;
  }
  __syncthreads();

  const int f = *flag;
  const int e0 = blockIdx.x * EPB + tid * 8;
  unsigned pk[8]; int bk[8]; int lr[8];
  if (e0 + 8 <= NE) {
    int sv[8], dv[8];
    if (f) {
      const int4* ps = (const int4*)(ei + 2 * (size_t)e0);
      const int4* pd = (const int4*)(ei + 2 * (size_t)NE + 2 * (size_t)e0);
      int4 a = ps[0], b = ps[1], c = ps[2], d = ps[3];
      sv[0]=a.x; sv[1]=a.z; sv[2]=b.x; sv[3]=b.z; sv[4]=c.x; sv[5]=c.z; sv[6]=d.x; sv[7]=d.z;
      a = pd[0]; b = pd[1]; c = pd[2]; d = pd[3];
      dv[0]=a.x; dv[1]=a.z; dv[2]=b.x; dv[3]=b.z; dv[4]=c.x; dv[5]=c.z; dv[6]=d.x; dv[7]=d.z;
    } else {
      const int4* ps = (const int4*)(ei + e0);
      const int4* pd = (const int4*)(ei + (size_t)NE + e0);
      int4 a = ps[0], b = ps[1];
      sv[0]=a.x; sv[1]=a.y; sv[2]=a.z; sv[3]=a.w; sv[4]=b.x; sv[5]=b.y; sv[6]=b.z; sv[7]=b.w;
      a = pd[0]; b = pd[1];
      dv[0]=a.x; dv[1]=a.y; dv[2]=a.z; dv[3]=a.w; dv[4]=b.x; dv[5]=b.y; dv[6]=b.z; dv[7]=b.w;
    }
#pragma unroll
    for (int j = 0; j < 8; ++j) {
      bk[j] = dv[j] >> 8;
      pk[j] = (unsigned)sv[j] | ((unsigned)(dv[j] & 255) << 16);
      lr[j] = atomicAdd(&cnt[bk[j]], 1);
    }
  } else {
    for (int j = 0; j < 8; ++j) {
      int e = e0 + j;
      bk[j] = -1;
      if (e < NE) {
        int src = f ? ei[2 * (size_t)e] : ei[e];
        int dst = f ? ei[2 * ((size_t)NE + e)] : ei[NE + e];
        bk[j] = dst >> 8;
        pk[j] = (unsigned)src | ((unsigned)(dst & 255) << 16);
        lr[j] = atomicAdd(&cnt[bk[j]], 1);
      }
    }
  }
  __syncthreads();
  if (tid < NBUK)
    off[tid] = cnt[tid] ? lbase[tid] + atomicAdd(&gcur[tid], cnt[tid]) : 0;
  __syncthreads();
#pragma unroll
  for (int j = 0; j < 8; ++j)
    if (bk[j] >= 0) ebuf[off[bk[j]] + lr[j]] = pk[j];
}

// Block-local counting sort per bucket (bases recomputed locally from gcnt):
// 256-counter LDS histogram + scan, write src (ushort) node-sorted; emit offs.
__global__ __launch_bounds__(512) void nsort_k(const unsigned* __restrict__ ebuf,
                                               const int* __restrict__ gcnt,
                                               int* __restrict__ offs,
                                               unsigned short* __restrict__ srt) {
  __shared__ int lbase[NBUK];
  __shared__ int cnt[256];
  __shared__ int cur[256];
  __shared__ int wsum[8];
  const int b = blockIdx.x, tid = threadIdx.x;
  const int lane = tid & 63, wv = tid >> 6;
  if (tid < 256) cnt[tid] = 0;
  if (wv < 4) {  // scan gcnt -> lbase
    int v = (tid < NBUK) ? gcnt[tid] : 0;
    int s = v;
#pragma unroll
    for (int d = 1; d < 64; d <<= 1) {
      int t = __shfl_up(s, d, 64);
      if (lane >= d) s += t;
    }
    if (lane == 63) wsum[wv] = s;
    __syncthreads();
    int woff = 0;
    for (int k = 0; k < wv; ++k) woff += wsum[k];
    if (tid < NBUK) lbase[tid] = woff + s - v;
  } else {
    __syncthreads();
  }
  __syncthreads();
  const int beg = lbase[b], end = beg + gcnt[b];
  for (int e = beg + tid; e < end; e += 512)
    atomicAdd(&cnt[ebuf[e] >> 16], 1);
  __syncthreads();
  int v2 = 0, s2 = 0;
  if (tid < 256) {
    v2 = cnt[tid]; s2 = v2;
#pragma unroll
    for (int d = 1; d < 64; d <<= 1) {
      int t = __shfl_up(s2, d, 64);
      if (lane >= d) s2 += t;
    }
    if (lane == 63) wsum[4 + wv] = s2;
  }
  __syncthreads();
  if (tid < 256) {
    int woff = 0;
    for (int k = 0; k < wv; ++k) woff += wsum[4 + k];
    int excl = woff + s2 - v2;
    cur[tid] = beg + excl;
    int node = (b << 8) + tid;
    if (node < NN) offs[node] = beg + excl;
  }
  if (b == NBUK - 1 && tid == 0) offs[NN] = NE;
  __syncthreads();
  for (int e = beg + tid; e < end; e += 512) {
    unsigned p = ebuf[e];
    int slot = atomicAdd(&cur[p >> 16], 1);
    srt[slot] = (unsigned short)(p & 0xffffu);
  }
}

// One wave per node, 16-deep gather pipeline, fp32 register accumulation
// (2 ch/lane, split chains), single bf16 row write.
__global__ __launch_bounds__(256) void agg_k(const unsigned short* __restrict__ srt,
                                             const int* __restrict__ offs,
                                             const unsigned short* __restrict__ hb,
                                             unsigned short* __restrict__ Sb) {
  const int w = (int)((blockIdx.x * 256u + threadIdx.x) >> 6);  // node id
  const int l2 = (threadIdx.x & 63) * 2;
  const unsigned short* hbl = hb + l2;
  const int beg = offs[w], end = offs[w + 1];
  float ax0 = 0.f, ay0 = 0.f, ax1 = 0.f, ay1 = 0.f;
  int e = beg;
  for (; e + 16 <= end; e += 16) {
    unsigned v[16];
#pragma unroll
    for (int j = 0; j < 16; ++j)
      v[j] = *(const unsigned*)(hbl + (size_t)srt[e + j] * D);
#pragma unroll
    for (int j = 0; j < 16; j += 2) {
      ax0 += b2f((unsigned short)(v[j] & 0xffffu));
      ay0 += b2f((unsigned short)(v[j] >> 16));
      ax1 += b2f((unsigned short)(v[j + 1] & 0xffffu));
      ay1 += b2f((unsigned short)(v[j + 1] >> 16));
    }
  }
  for (; e + 4 <= end; e += 4) {
    unsigned v[4];
#pragma unroll
    for (int j = 0; j < 4; ++j)
      v[j] = *(const unsigned*)(hbl + (size_t)srt[e + j] * D);
#pragma unroll
    for (int j = 0; j < 4; j += 2) {
      ax0 += b2f((unsigned short)(v[j] & 0xffffu));
      ay0 += b2f((unsigned short)(v[j] >> 16));
      ax1 += b2f((unsigned short)(v[j + 1] & 0xffffu));
      ay1 += b2f((unsigned short)(v[j + 1] >> 16));
    }
  }
  for (; e < end; ++e) {
    unsigned v = *(const unsigned*)(hbl + (size_t)srt[e] * D);
    ax0 += b2f((unsigned short)(v & 0xffffu));
    ay0 += b2f((unsigned short)(v >> 16));
  }
  const float ax = ax0 + ax1, ay = ay0 + ay1;
  unsigned o = (unsigned)f2b(ax) | ((unsigned)f2b(ay) << 16);
  *(unsigned*)(Sb + (size_t)w * D + l2) = o;
}

// out = relu([h | agg] @ [W1 | Wc]^T + b), bf16 MFMA 16x16x32, K=256, N=128.
__global__ __launch_bounds__(256) void gemm_k(const unsigned short* __restrict__ hb,
                                              const unsigned short* __restrict__ Sb,
                                              const unsigned short* __restrict__ W1b,
                                              const unsigned short* __restrict__ Wcb,
                                              const float* __restrict__ bias,
                                              float* __restrict__ out) {
  const int wave = threadIdx.x >> 6;
  const int lane = threadIdx.x & 63;
  const int r = lane & 15;
  const int g = lane >> 4;
  const int row0 = blockIdx.x * 64 + wave * 16;
  const int row = min(row0 + r, NN - 1);

  f32x4 acc[8];
#pragma unroll
  for (int t = 0; t < 8; ++t) acc[t] = (f32x4){0.f, 0.f, 0.f, 0.f};

#pragma unroll
  for (int c = 0; c < 8; ++c) {
    const int k0 = (c & 3) * 32 + g * 8;
    const unsigned short* A = (c < 4) ? hb : Sb;
    short8 a = *(const short8*)(A + (size_t)row * D + k0);
    const unsigned short* W = (c < 4) ? W1b : Wcb;
#pragma unroll
    for (int t = 0; t < 8; ++t) {
      short8 bfr = *(const short8*)(W + (size_t)(t * 16 + r) * D + k0);
      acc[t] = __builtin_amdgcn_mfma_f32_16x16x32_bf16(a, bfr, acc[t], 0, 0, 0);
    }
  }

#pragma unroll
  for (int t = 0; t < 8; ++t) {
    const int col = t * 16 + r;
    const float bv = bias[col];
#pragma unroll
    for (int j = 0; j < 4; ++j) {
      const int orow = row0 + g * 4 + j;
      if (orow < NN) {
        float v = acc[t][j] + bv;
        out[(size_t)orow * D + col] = v > 0.f ? v : 0.f;
      }
    }
  }
}

extern "C" void kernel_launch(void* const* d_in, const int* in_sizes, int n_in,
                              void* d_out, int out_size, void* d_ws, size_t ws_size,
                              hipStream_t stream) {
  const float* h  = (const float*)d_in[0];
  const int*   ei = (const int*)d_in[1];
  const float* Wm = (const float*)d_in[2];
  const float* Wu = (const float*)d_in[3];
  const float* bu = (const float*)d_in[4];
  float* out = (float*)d_out;

  char* ws = (char*)d_ws;
  unsigned short* Sb   = (unsigned short*)(ws);              // 12,800,000 B
  unsigned short* hb   = (unsigned short*)(ws + 12800000);   // 12,800,000 B
  unsigned*       ebuf = (unsigned*)(ws + 25600000);         //  6,400,000 B
  unsigned short* srt  = (unsigned short*)(ws + 32000000);   //  3,200,000 B
  int*            offs = (int*)(ws + 35200000);              //    200,016 B (NN+1)
  int*            gcnt = (int*)(ws + 35400016);              //      1,024 B
  int*            gcur = (int*)(ws + 35401040);              //      1,024 B
  unsigned short* W1b  = (unsigned short*)(ws + 35402064);   //     32,768 B
  unsigned short* Wcb  = (unsigned short*)(ws + 35434832);   //     32,768 B
  int*            flg  = (int*)(ws + 35467600);              //          4 B

  init_k<<<6315, 256, 0, stream>>>(h, hb, gcnt, gcur, Wm, Wu, W1b, Wcb, ei, flg);
  bhist_k<<<(NE + EPB - 1) / EPB, 256, 0, stream>>>(ei, flg, gcnt);     // 782
  bfill_k<<<(NE + EPB - 1) / EPB, 256, 0, stream>>>(ei, flg, gcnt, gcur, ebuf);
  nsort_k<<<NBUK, 512, 0, stream>>>(ebuf, gcnt, offs, srt);             // 196
  agg_k<<<(NN * 64) / 256, 256, 0, stream>>>(srt, offs, hb, Sb);        // 12500
  gemm_k<<<(NN + 63) / 64, 256, 0, stream>>>(hb, Sb, W1b, Wcb, bu, out);
}

// Round 6
// 142.825 us; speedup vs baseline: 10.4455x; 1.2236x over previous
//
#include <hip/hip_runtime.h>
#include <hip/hip_bf16.h>

#define NN   50000
#define NE   1600000
#define D    128
#define NBUK 391      // ceil(NN/128) buckets of 128 nodes
#define CAP  5120     // per-bucket edge capacity (mean 4092, +16 sigma)
#define EPB  2048     // edges per block in fill

typedef __attribute__((ext_vector_type(8))) short short8;
typedef __attribute__((ext_vector_type(4))) float f32x4;

__device__ __forceinline__ unsigned short f2b(float x) {
  unsigned u = __float_as_uint(x);
  u += 0x7fffu + ((u >> 16) & 1u);
  return (unsigned short)(u >> 16);
}
__device__ __forceinline__ float b2f(unsigned short v) {
  return __uint_as_float(((unsigned)v) << 16);
}

// Fused: prep (h->bf16, zero gcur) | wprep (fold W2@Wmsg) | int64-detect.
__global__ __launch_bounds__(256) void init_k(const float* __restrict__ h,
                                              unsigned short* __restrict__ hb,
                                              int* __restrict__ gcur,
                                              const float* __restrict__ Wm,
                                              const float* __restrict__ Wu,
                                              unsigned short* __restrict__ W1b,
                                              unsigned short* __restrict__ Wcb,
                                              const int* __restrict__ ei,
                                              int* __restrict__ flg) {
  __shared__ int nz;
  const int blk = blockIdx.x;
  if (blk < 6250) {                     // prep: 6250*256 float4 groups
    int i = blk * 256 + threadIdx.x;
    float4 x = ((const float4*)h)[i];
    ushort4 o;
    o.x = f2b(x.x); o.y = f2b(x.y); o.z = f2b(x.z); o.w = f2b(x.w);
    ((ushort4*)hb)[i] = o;
    if (i < NBUK) gcur[i] = 0;
  } else if (blk < 6314) {              // wprep: 64 blocks -> 16384 threads
    int tid = (blk - 6250) * 256 + threadIdx.x;
    int o = tid >> 7, j = tid & 127;
    W1b[tid] = f2b(Wu[o * 256 + j]);
    float acc = 0.f;
#pragma unroll 4
    for (int k = 0; k < 128; ++k)
      acc += Wu[o * 256 + 128 + k] * Wm[k * 128 + j];
    Wcb[tid] = f2b(acc);
  } else {                              // detect: odd int32 words all-zero => int64
    if (threadIdx.x == 0) nz = 0;
    __syncthreads();
    int idx = 1 + 2 * ((int)threadIdx.x * (NE / 256));
    if (ei[idx] != 0) atomicOr(&nz, 1);
    __syncthreads();
    if (threadIdx.x == 0) *flg = (nz == 0) ? 1 : 0;
  }
}

// Bucket the edges into fixed-capacity slots: LDS local ranks + one bulk
// global reservation per (block,bucket); packed (dstLocal<<16 | src).
__global__ __launch_bounds__(256) void bfill_k(const int* __restrict__ ei,
                                               const int* __restrict__ flag,
                                               int* __restrict__ gcur,
                                               unsigned* __restrict__ ebuf) {
  __shared__ int cnt[NBUK];
  __shared__ int off[NBUK];
  const int tid = threadIdx.x;
  for (int t = tid; t < NBUK; t += 256) cnt[t] = 0;
  __syncthreads();
  const int f = *flag;
  const int e0 = blockIdx.x * EPB + tid * 8;
  unsigned pk[8]; int bk[8]; int lr[8];
  if (e0 + 8 <= NE) {
    int sv[8], dv[8];
    if (f) {
      const int4* ps = (const int4*)(ei + 2 * (size_t)e0);
      const int4* pd = (const int4*)(ei + 2 * (size_t)NE + 2 * (size_t)e0);
      int4 a = ps[0], b = ps[1], c = ps[2], d = ps[3];
      sv[0]=a.x; sv[1]=a.z; sv[2]=b.x; sv[3]=b.z; sv[4]=c.x; sv[5]=c.z; sv[6]=d.x; sv[7]=d.z;
      a = pd[0]; b = pd[1]; c = pd[2]; d = pd[3];
      dv[0]=a.x; dv[1]=a.z; dv[2]=b.x; dv[3]=b.z; dv[4]=c.x; dv[5]=c.z; dv[6]=d.x; dv[7]=d.z;
    } else {
      const int4* ps = (const int4*)(ei + e0);
      const int4* pd = (const int4*)(ei + (size_t)NE + e0);
      int4 a = ps[0], b = ps[1];
      sv[0]=a.x; sv[1]=a.y; sv[2]=a.z; sv[3]=a.w; sv[4]=b.x; sv[5]=b.y; sv[6]=b.z; sv[7]=b.w;
      a = pd[0]; b = pd[1];
      dv[0]=a.x; dv[1]=a.y; dv[2]=a.z; dv[3]=a.w; dv[4]=b.x; dv[5]=b.y; dv[6]=b.z; dv[7]=b.w;
    }
#pragma unroll
    for (int j = 0; j < 8; ++j) {
      bk[j] = dv[j] >> 7;
      pk[j] = (unsigned)sv[j] | ((unsigned)(dv[j] & 127) << 16);
      lr[j] = atomicAdd(&cnt[bk[j]], 1);
    }
  } else {
    for (int j = 0; j < 8; ++j) {
      int e = e0 + j;
      bk[j] = -1;
      if (e < NE) {
        int src = f ? ei[2 * (size_t)e] : ei[e];
        int dst = f ? ei[2 * ((size_t)NE + e)] : ei[NE + e];
        bk[j] = dst >> 7;
        pk[j] = (unsigned)src | ((unsigned)(dst & 127) << 16);
        lr[j] = atomicAdd(&cnt[bk[j]], 1);
      }
    }
  }
  __syncthreads();
  for (int t = tid; t < NBUK; t += 256)
    off[t] = cnt[t] ? atomicAdd(&gcur[t], cnt[t]) : 0;
  __syncthreads();
#pragma unroll
  for (int j = 0; j < 8; ++j) {
    if (bk[j] >= 0) {
      int idx = off[bk[j]] + lr[j];
      if (idx < CAP) ebuf[(size_t)bk[j] * CAP + idx] = pk[j];
    }
  }
}

// One block per bucket: counting-sort the bucket's edges into LDS, then
// 8 waves x 16 nodes each: register fp32 aggregation (2 ch/lane), 16-deep
// gather pipeline, single bf16 row write per node.
__global__ __launch_bounds__(512) void sortagg_k(const unsigned* __restrict__ ebuf,
                                                 const int* __restrict__ gcur,
                                                 const unsigned short* __restrict__ hb,
                                                 unsigned short* __restrict__ Sb) {
  __shared__ unsigned short srt[CAP];
  __shared__ int cnt[128];
  __shared__ int ofs[129];
  __shared__ int cur[128];
  __shared__ int wsum[2];
  const int b = blockIdx.x, tid = threadIdx.x;
  const int lane = tid & 63, wv = tid >> 6;
  if (tid < 128) cnt[tid] = 0;
  __syncthreads();
  const int count = min(gcur[b], CAP);
  const unsigned* eb = ebuf + (size_t)b * CAP;
  for (int e = tid; e < count; e += 512)
    atomicAdd(&cnt[eb[e] >> 16], 1);
  __syncthreads();
  int v = 0, s = 0;
  if (tid < 128) {  // waves 0,1 fully active: wave-uniform scan
    v = cnt[tid]; s = v;
#pragma unroll
    for (int d = 1; d < 64; d <<= 1) {
      int t = __shfl_up(s, d, 64);
      if (lane >= d) s += t;
    }
    if (lane == 63) wsum[wv] = s;
  }
  __syncthreads();
  if (tid < 128) {
    int excl = (wv ? wsum[0] : 0) + s - v;
    ofs[tid] = excl;
    cur[tid] = excl;
  }
  if (tid == 0) ofs[128] = count;
  __syncthreads();
  for (int e = tid; e < count; e += 512) {
    unsigned p = eb[e];
    int slot = atomicAdd(&cur[p >> 16], 1);
    srt[slot] = (unsigned short)(p & 0xffffu);
  }
  __syncthreads();

  const int l2 = lane * 2;
  const unsigned short* hbl = hb + l2;
#pragma unroll 1
  for (int k = 0; k < 16; ++k) {
    const int n = wv * 16 + k;
    const int node = (b << 7) + n;
    if (node >= NN) break;
    const int beg = ofs[n], end = ofs[n + 1];
    float ax0 = 0.f, ay0 = 0.f, ax1 = 0.f, ay1 = 0.f;
    int e = beg;
    for (; e + 16 <= end; e += 16) {
      unsigned vv[16];
#pragma unroll
      for (int j = 0; j < 16; ++j)
        vv[j] = *(const unsigned*)(hbl + (size_t)srt[e + j] * D);
#pragma unroll
      for (int j = 0; j < 16; j += 2) {
        ax0 += b2f((unsigned short)(vv[j] & 0xffffu));
        ay0 += b2f((unsigned short)(vv[j] >> 16));
        ax1 += b2f((unsigned short)(vv[j + 1] & 0xffffu));
        ay1 += b2f((unsigned short)(vv[j + 1] >> 16));
      }
    }
    for (; e + 4 <= end; e += 4) {
      unsigned vv[4];
#pragma unroll
      for (int j = 0; j < 4; ++j)
        vv[j] = *(const unsigned*)(hbl + (size_t)srt[e + j] * D);
#pragma unroll
      for (int j = 0; j < 4; j += 2) {
        ax0 += b2f((unsigned short)(vv[j] & 0xffffu));
        ay0 += b2f((unsigned short)(vv[j] >> 16));
        ax1 += b2f((unsigned short)(vv[j + 1] & 0xffffu));
        ay1 += b2f((unsigned short)(vv[j + 1] >> 16));
      }
    }
    for (; e < end; ++e) {
      unsigned vv = *(const unsigned*)(hbl + (size_t)srt[e] * D);
      ax0 += b2f((unsigned short)(vv & 0xffffu));
      ay0 += b2f((unsigned short)(vv >> 16));
    }
    unsigned o = (unsigned)f2b(ax0 + ax1) | ((unsigned)f2b(ay0 + ay1) << 16);
    *(unsigned*)(Sb + (size_t)node * D + l2) = o;
  }
}

// out = relu([h | agg] @ [W1 | Wc]^T + b), bf16 MFMA 16x16x32, K=256, N=128.
__global__ __launch_bounds__(256) void gemm_k(const unsigned short* __restrict__ hb,
                                              const unsigned short* __restrict__ Sb,
                                              const unsigned short* __restrict__ W1b,
                                              const unsigned short* __restrict__ Wcb,
                                              const float* __restrict__ bias,
                                              float* __restrict__ out) {
  const int wave = threadIdx.x >> 6;
  const int lane = threadIdx.x & 63;
  const int r = lane & 15;
  const int g = lane >> 4;
  const int row0 = blockIdx.x * 64 + wave * 16;
  const int row = min(row0 + r, NN - 1);

  f32x4 acc[8];
#pragma unroll
  for (int t = 0; t < 8; ++t) acc[t] = (f32x4){0.f, 0.f, 0.f, 0.f};

#pragma unroll
  for (int c = 0; c < 8; ++c) {
    const int k0 = (c & 3) * 32 + g * 8;
    const unsigned short* A = (c < 4) ? hb : Sb;
    short8 a = *(const short8*)(A + (size_t)row * D + k0);
    const unsigned short* W = (c < 4) ? W1b : Wcb;
#pragma unroll
    for (int t = 0; t < 8; ++t) {
      short8 bfr = *(const short8*)(W + (size_t)(t * 16 + r) * D + k0);
      acc[t] = __builtin_amdgcn_mfma_f32_16x16x32_bf16(a, bfr, acc[t], 0, 0, 0);
    }
  }

#pragma unroll
  for (int t = 0; t < 8; ++t) {
    const int col = t * 16 + r;
    const float bv = bias[col];
#pragma unroll
    for (int j = 0; j < 4; ++j) {
      const int orow = row0 + g * 4 + j;
      if (orow < NN) {
        float vv = acc[t][j] + bv;
        out[(size_t)orow * D + col] = vv > 0.f ? vv : 0.f;
      }
    }
  }
}

extern "C" void kernel_launch(void* const* d_in, const int* in_sizes, int n_in,
                              void* d_out, int out_size, void* d_ws, size_t ws_size,
                              hipStream_t stream) {
  const float* h  = (const float*)d_in[0];
  const int*   ei = (const int*)d_in[1];
  const float* Wm = (const float*)d_in[2];
  const float* Wu = (const float*)d_in[3];
  const float* bu = (const float*)d_in[4];
  float* out = (float*)d_out;

  char* ws = (char*)d_ws;
  unsigned short* Sb   = (unsigned short*)(ws);              // 12,800,000 B
  unsigned short* hb   = (unsigned short*)(ws + 12800000);   // 12,800,000 B
  unsigned*       ebuf = (unsigned*)(ws + 25600000);         //  8,007,680 B (391*5120*4)
  int*            gcur = (int*)(ws + 33607680);              //      2,048 B
  unsigned short* W1b  = (unsigned short*)(ws + 33609728);   //     32,768 B
  unsigned short* Wcb  = (unsigned short*)(ws + 33642496);   //     32,768 B
  int*            flg  = (int*)(ws + 33675264);              //          4 B

  init_k<<<6315, 256, 0, stream>>>(h, hb, gcur, Wm, Wu, W1b, Wcb, ei, flg);
  bfill_k<<<(NE + EPB - 1) / EPB, 256, 0, stream>>>(ei, flg, gcur, ebuf);  // 782
  sortagg_k<<<NBUK, 512, 0, stream>>>(ebuf, gcur, hb, Sb);                 // 391
  gemm_k<<<(NN + 63) / 64, 256, 0, stream>>>(hb, Sb, W1b, Wcb, bu, out);   // 782
}

// Round 7
// 117.436 us; speedup vs baseline: 12.7037x; 1.2162x over previous
//
#include <hip/hip_runtime.h>
#include <hip/hip_bf16.h>

#define NN   50000
#define NE   1600000
#define D    128
#define NBUK 391      // ceil(NN/128) buckets of 128 nodes
#define CAP  5120     // per-bucket edge capacity (mean 4092, +16 sigma)
#define EPB  4096     // edges per block in fill (512 thr x 8)
#define ASTR 136      // aggL row stride in ushorts (272 B: 16B-aligned, bank-uniform)

typedef __attribute__((ext_vector_type(8))) short short8;
typedef __attribute__((ext_vector_type(4))) float f32x4;

__device__ __forceinline__ unsigned short f2b(float x) {
  unsigned u = __float_as_uint(x);
  u += 0x7fffu + ((u >> 16) & 1u);
  return (unsigned short)(u >> 16);
}
__device__ __forceinline__ float b2f(unsigned short v) {
  return __uint_as_float(((unsigned)v) << 16);
}

// Fused: prep (h->bf16, zero gcur) | wprep (fold W2@Wmsg) | int64-detect.
__global__ __launch_bounds__(256) void init_k(const float* __restrict__ h,
                                              unsigned short* __restrict__ hb,
                                              int* __restrict__ gcur,
                                              const float* __restrict__ Wm,
                                              const float* __restrict__ Wu,
                                              unsigned short* __restrict__ W1b,
                                              unsigned short* __restrict__ Wcb,
                                              const int* __restrict__ ei,
                                              int* __restrict__ flg) {
  __shared__ int nz;
  const int blk = blockIdx.x;
  if (blk < 6250) {                     // prep: 6250*256 float4 groups
    int i = blk * 256 + threadIdx.x;
    float4 x = ((const float4*)h)[i];
    ushort4 o;
    o.x = f2b(x.x); o.y = f2b(x.y); o.z = f2b(x.z); o.w = f2b(x.w);
    ((ushort4*)hb)[i] = o;
    if (i < NBUK) gcur[i] = 0;
  } else if (blk < 6314) {              // wprep: 64 blocks -> 16384 threads
    int tid = (blk - 6250) * 256 + threadIdx.x;
    int o = tid >> 7, j = tid & 127;
    W1b[tid] = f2b(Wu[o * 256 + j]);
    float acc = 0.f;
#pragma unroll 4
    for (int k = 0; k < 128; ++k)
      acc += Wu[o * 256 + 128 + k] * Wm[k * 128 + j];
    Wcb[tid] = f2b(acc);
  } else {                              // detect: odd int32 words all-zero => int64
    if (threadIdx.x == 0) nz = 0;
    __syncthreads();
    int idx = 1 + 2 * ((int)threadIdx.x * (NE / 256));
    if (ei[idx] != 0) atomicOr(&nz, 1);
    __syncthreads();
    if (threadIdx.x == 0) *flg = (nz == 0) ? 1 : 0;
  }
}

// Bucket the edges into fixed-capacity slots: LDS local ranks + one bulk
// global reservation per (block,bucket); packed (dstLocal<<16 | src).
__global__ __launch_bounds__(512) void bfill_k(const int* __restrict__ ei,
                                               const int* __restrict__ flag,
                                               int* __restrict__ gcur,
                                               unsigned* __restrict__ ebuf) {
  __shared__ int cnt[NBUK];
  __shared__ int off[NBUK];
  const int tid = threadIdx.x;
  if (tid < NBUK) cnt[tid] = 0;
  __syncthreads();
  const int f = *flag;
  const int e0 = blockIdx.x * EPB + tid * 8;
  unsigned pk[8]; int bk[8]; int lr[8];
  if (e0 + 8 <= NE) {
    int sv[8], dv[8];
    if (f) {
      const int4* ps = (const int4*)(ei + 2 * (size_t)e0);
      const int4* pd = (const int4*)(ei + 2 * (size_t)NE + 2 * (size_t)e0);
      int4 a = ps[0], b = ps[1], c = ps[2], d = ps[3];
      sv[0]=a.x; sv[1]=a.z; sv[2]=b.x; sv[3]=b.z; sv[4]=c.x; sv[5]=c.z; sv[6]=d.x; sv[7]=d.z;
      a = pd[0]; b = pd[1]; c = pd[2]; d = pd[3];
      dv[0]=a.x; dv[1]=a.z; dv[2]=b.x; dv[3]=b.z; dv[4]=c.x; dv[5]=c.z; dv[6]=d.x; dv[7]=d.z;
    } else {
      const int4* ps = (const int4*)(ei + e0);
      const int4* pd = (const int4*)(ei + (size_t)NE + e0);
      int4 a = ps[0], b = ps[1];
      sv[0]=a.x; sv[1]=a.y; sv[2]=a.z; sv[3]=a.w; sv[4]=b.x; sv[5]=b.y; sv[6]=b.z; sv[7]=b.w;
      a = pd[0]; b = pd[1];
      dv[0]=a.x; dv[1]=a.y; dv[2]=a.z; dv[3]=a.w; dv[4]=b.x; dv[5]=b.y; dv[6]=b.z; dv[7]=b.w;
    }
#pragma unroll
    for (int j = 0; j < 8; ++j) {
      bk[j] = dv[j] >> 7;
      pk[j] = (unsigned)sv[j] | ((unsigned)(dv[j] & 127) << 16);
      lr[j] = atomicAdd(&cnt[bk[j]], 1);
    }
  } else {
    for (int j = 0; j < 8; ++j) {
      int e = e0 + j;
      bk[j] = -1;
      if (e < NE) {
        int src = f ? ei[2 * (size_t)e] : ei[e];
        int dst = f ? ei[2 * ((size_t)NE + e)] : ei[NE + e];
        bk[j] = dst >> 7;
        pk[j] = (unsigned)src | ((unsigned)(dst & 127) << 16);
        lr[j] = atomicAdd(&cnt[bk[j]], 1);
      }
    }
  }
  __syncthreads();
  if (tid < NBUK)
    off[tid] = cnt[tid] ? atomicAdd(&gcur[tid], cnt[tid]) : 0;
  __syncthreads();
#pragma unroll
  for (int j = 0; j < 8; ++j) {
    if (bk[j] >= 0) {
      int idx = off[bk[j]] + lr[j];
      if (idx < CAP) ebuf[(size_t)bk[j] * CAP + idx] = pk[j];
    }
  }
}

// One block per bucket, 16 waves:
//  (1) counting-sort the bucket's edges into LDS (srt);
//  (2) each wave aggregates 8 node rows in fp32 registers (16-deep gather
//      pipeline), writes bf16 rows into LDS aggL;
//  (3) MFMA epilogue on [hb | aggL] x [W1|Wc]^T + bias, ReLU, store to out.
__global__ __launch_bounds__(1024, 8) void sortagg_k(const unsigned* __restrict__ ebuf,
                                                     const int* __restrict__ gcur,
                                                     const unsigned short* __restrict__ hb,
                                                     const unsigned short* __restrict__ W1b,
                                                     const unsigned short* __restrict__ Wcb,
                                                     const float* __restrict__ bias,
                                                     float* __restrict__ out) {
  __shared__ unsigned short srt[CAP];
  __shared__ __align__(16) unsigned short aggL[128 * ASTR];
  __shared__ int cnt[128];
  __shared__ int ofs[129];
  __shared__ int cur[128];
  __shared__ int wsum[2];
  const int b = blockIdx.x, tid = threadIdx.x;
  const int lane = tid & 63, wv = tid >> 6;  // 16 waves
  if (tid < 128) cnt[tid] = 0;
  __syncthreads();
  const int count = min(gcur[b], CAP);
  const unsigned* eb = ebuf + (size_t)b * CAP;
  for (int e = tid; e < count; e += 1024)
    atomicAdd(&cnt[eb[e] >> 16], 1);
  __syncthreads();
  int v = 0, s = 0;
  if (tid < 128) {  // waves 0,1: wave-uniform scan of 128 counters
    v = cnt[tid]; s = v;
#pragma unroll
    for (int d = 1; d < 64; d <<= 1) {
      int t = __shfl_up(s, d, 64);
      if (lane >= d) s += t;
    }
    if (lane == 63) wsum[wv] = s;
  }
  __syncthreads();
  if (tid < 128) {
    int excl = (wv ? wsum[0] : 0) + s - v;
    ofs[tid] = excl;
    cur[tid] = excl;
  }
  if (tid == 0) ofs[128] = count;
  __syncthreads();
  for (int e = tid; e < count; e += 1024) {
    unsigned p = eb[e];
    int slot = atomicAdd(&cur[p >> 16], 1);
    srt[slot] = (unsigned short)(p & 0xffffu);
  }
  __syncthreads();

  // ---- aggregation: wave wv owns local nodes wv*8 .. wv*8+7 ----
  const int l2 = lane * 2;
  const unsigned short* hbl = hb + l2;
#pragma unroll 1
  for (int k = 0; k < 8; ++k) {
    const int n = wv * 8 + k;
    const int beg = ofs[n], end = ofs[n + 1];
    float ax0 = 0.f, ay0 = 0.f, ax1 = 0.f, ay1 = 0.f;
    int e = beg;
    for (; e + 16 <= end; e += 16) {
      unsigned vv[16];
#pragma unroll
      for (int j = 0; j < 16; ++j)
        vv[j] = *(const unsigned*)(hbl + (size_t)srt[e + j] * D);
#pragma unroll
      for (int j = 0; j < 16; j += 2) {
        ax0 += b2f((unsigned short)(vv[j] & 0xffffu));
        ay0 += b2f((unsigned short)(vv[j] >> 16));
        ax1 += b2f((unsigned short)(vv[j + 1] & 0xffffu));
        ay1 += b2f((unsigned short)(vv[j + 1] >> 16));
      }
    }
    for (; e + 4 <= end; e += 4) {
      unsigned vv[4];
#pragma unroll
      for (int j = 0; j < 4; ++j)
        vv[j] = *(const unsigned*)(hbl + (size_t)srt[e + j] * D);
#pragma unroll
      for (int j = 0; j < 4; j += 2) {
        ax0 += b2f((unsigned short)(vv[j] & 0xffffu));
        ay0 += b2f((unsigned short)(vv[j] >> 16));
        ax1 += b2f((unsigned short)(vv[j + 1] & 0xffffu));
        ay1 += b2f((unsigned short)(vv[j + 1] >> 16));
      }
    }
    for (; e < end; ++e) {
      unsigned vv = *(const unsigned*)(hbl + (size_t)srt[e] * D);
      ax0 += b2f((unsigned short)(vv & 0xffffu));
      ay0 += b2f((unsigned short)(vv >> 16));
    }
    unsigned o = (unsigned)f2b(ax0 + ax1) | ((unsigned)f2b(ay0 + ay1) << 16);
    ((unsigned*)aggL)[n * (ASTR / 2) + lane] = o;  // bank = (4n+lane)%32: 2-way, free
  }
  __syncthreads();

  // ---- MFMA epilogue: 8 row-tiles of 16; wave pair (2i,2i+1) splits cols ----
  const int r = lane & 15, g = lane >> 4;
  const int tile = wv >> 1;          // 0..7
  const int t0 = (wv & 1) * 4;       // col-tile offset: 0 or 4
  const int rowL = tile * 16 + r;    // local A row
  const int nodeA = min(b * 128 + rowL, NN - 1);

  f32x4 acc[4];
#pragma unroll
  for (int t = 0; t < 4; ++t) acc[t] = (f32x4){0.f, 0.f, 0.f, 0.f};

#pragma unroll
  for (int c = 0; c < 8; ++c) {
    const int k0 = (c & 3) * 32 + g * 8;
    short8 a;
    if (c < 4) {
      a = *(const short8*)(hb + (size_t)nodeA * D + k0);
    } else {
      a = *(const short8*)(aggL + rowL * ASTR + k0);  // ds_read_b128, bank-uniform
    }
    const unsigned short* W = (c < 4) ? W1b : Wcb;
#pragma unroll
    for (int tt = 0; tt < 4; ++tt) {
      short8 bfr = *(const short8*)(W + (size_t)((t0 + tt) * 16 + r) * D + k0);
      acc[tt] = __builtin_amdgcn_mfma_f32_16x16x32_bf16(a, bfr, acc[tt], 0, 0, 0);
    }
  }

#pragma unroll
  for (int tt = 0; tt < 4; ++tt) {
    const int col = (t0 + tt) * 16 + r;
    const float bv = bias[col];
#pragma unroll
    for (int j = 0; j < 4; ++j) {
      const int orow = b * 128 + tile * 16 + g * 4 + j;
      if (orow < NN) {
        float vv = acc[tt][j] + bv;
        out[(size_t)orow * D + col] = vv > 0.f ? vv : 0.f;
      }
    }
  }
}

extern "C" void kernel_launch(void* const* d_in, const int* in_sizes, int n_in,
                              void* d_out, int out_size, void* d_ws, size_t ws_size,
                              hipStream_t stream) {
  const float* h  = (const float*)d_in[0];
  const int*   ei = (const int*)d_in[1];
  const float* Wm = (const float*)d_in[2];
  const float* Wu = (const float*)d_in[3];
  const float* bu = (const float*)d_in[4];
  float* out = (float*)d_out;

  char* ws = (char*)d_ws;
  unsigned short* hb   = (unsigned short*)(ws);              // 12,800,000 B
  unsigned*       ebuf = (unsigned*)(ws + 12800000);         //  8,007,680 B (391*5120*4)
  int*            gcur = (int*)(ws + 20807680);              //      2,048 B
  unsigned short* W1b  = (unsigned short*)(ws + 20809728);   //     32,768 B
  unsigned short* Wcb  = (unsigned short*)(ws + 20842496);   //     32,768 B
  int*            flg  = (int*)(ws + 20875264);              //          4 B

  init_k<<<6315, 256, 0, stream>>>(h, hb, gcur, Wm, Wu, W1b, Wcb, ei, flg);
  bfill_k<<<(NE + EPB - 1) / EPB, 512, 0, stream>>>(ei, flg, gcur, ebuf);     // 391
  sortagg_k<<<NBUK, 1024, 0, stream>>>(ebuf, gcur, hb, W1b, Wcb, bu, out);    // 391
}